// Round 17
// baseline (413.453 us; speedup 1.0000x reference)
//
#include <hip/hip_runtime.h>

// B=4, NQ=NK=2048, D_MODEL=1024, H=16, D_K=D_V=64; M = 8192.
// att_v uses PRE-softmax scores => att_v = scale * Q @ (K^T V).
// beta only needs row exp-sums of scores.
//
// ROUND 16: proj goes to 16 waves (1024 thr), same 256x256 tile; per-wave
// output 64x64 (acc 64 regs). Mechanism: 4 waves/SIMD intra-block TLP
// (was 2, barrier-lockstep). vmcnt chain re-derived fully fenced:
// per body issues B(T+1)[1]+A(T+3)[2]; vmcnt(2) drains A(T+2),B(T+1).

#define SCALE 0.125f
#define LOG2E 1.44269504088896f
#define SCLOG 0.18033688011112042f  // SCALE * LOG2E

typedef __attribute__((ext_vector_type(8))) short bf16x8;
typedef __attribute__((ext_vector_type(4))) short s16x4;
typedef __attribute__((ext_vector_type(4))) float f32x4;
typedef __attribute__((ext_vector_type(16))) float f32x16;

__device__ __forceinline__ float b2f(short x) {
  return __uint_as_float(((unsigned)(unsigned short)x) << 16);
}
__device__ __forceinline__ short f2b(float x) {
  unsigned u = __float_as_uint(x);
  unsigned r = (u + 0x7fffu + ((u >> 16) & 1u)) >> 16;
  return (short)r;
}
// native 2^x (v_exp_f32); inputs here are far from denormal/overflow edges.
__device__ __forceinline__ float fexp2(float x) {
  float r;
  asm("v_exp_f32 %0, %1" : "=v"(r) : "v"(x));
  return r;
}
// 8x f32 -> bf16x8 via packed converts (RTNE).
__device__ __forceinline__ bf16x8 cvt8(f32x4 lo, f32x4 hi) {
  unsigned u0, u1, u2, u3;
  asm("v_cvt_pk_bf16_f32 %0, %1, %2" : "=v"(u0) : "v"(lo[0]), "v"(lo[1]));
  asm("v_cvt_pk_bf16_f32 %0, %1, %2" : "=v"(u1) : "v"(lo[2]), "v"(lo[3]));
  asm("v_cvt_pk_bf16_f32 %0, %1, %2" : "=v"(u2) : "v"(hi[0]), "v"(hi[1]));
  asm("v_cvt_pk_bf16_f32 %0, %1, %2" : "=v"(u3) : "v"(hi[2]), "v"(hi[3]));
  union { unsigned u[4]; bf16x8 v; } r;
  r.u[0] = u0; r.u[1] = u1; r.u[2] = u2; r.u[3] = u3;
  return r.v;
}

// async global->LDS, 16B per lane. LDS dest must be uniform_base + lane*16.
__device__ __forceinline__ void gl2lds16(const short* g, short* l) {
  __builtin_amdgcn_global_load_lds(
      (const __attribute__((address_space(1))) unsigned int*)g,
      (__attribute__((address_space(3))) unsigned int*)l, 16, 0, 0);
}

// ---------------- weights: Wt[n][k] = bf16(W[k][n]), 1024x1024 each --------
__global__ __launch_bounds__(256) void wtrans_kernel(
    const float* W0, const float* W1, const float* W2, const float* W3, const float* W4,
    short* O0, short* O1, short* O2, short* O3, short* O4) {
  const float* Wp[5] = {W0, W1, W2, W3, W4};
  short* Op[5] = {O0, O1, O2, O3, O4};
  const float* W = Wp[blockIdx.z];
  short* O = Op[blockIdx.z];
  int n0 = blockIdx.x * 64, k0 = blockIdx.y * 64;
  __shared__ float ts[64 * 68];
  int tid = threadIdx.x;
  int r = tid >> 4, c = (tid & 15) * 4;
  for (int ir = 0; ir < 4; ++ir) {
    f32x4 v = *reinterpret_cast<const f32x4*>(&W[(size_t)(k0 + r + ir * 16) * 1024 + n0 + c]);
    *reinterpret_cast<f32x4*>(&ts[(r + ir * 16) * 68 + c]) = v;
  }
  __syncthreads();
  for (int ir = 0; ir < 4; ++ir) {
    int n = r + ir * 16;
    s16x4 o;
    for (int j = 0; j < 4; ++j) o[j] = f2b(ts[(c + j) * 68 + n]);
    *reinterpret_cast<s16x4*>(&O[(size_t)(n0 + n) * 1024 + k0 + c]) = o;
  }
}

// ===== 256x256 GEMM core, 16 waves, f32 A reg-staged + bf16 B gl2lds ======
// 1024 thr = 16 waves (4Mx4N), each owns 64x64. BK=32. A: depth-3 via 3 reg
// sets (p,q,r; 2 f32x4 each), 2 LDS buffers. B: 2 LDS buffers, staged at
// T+1. 64 KB LDS. 32x32x16 MFMA, 8/body/wave.
// Fenced vmcnt: body T issues B(T+1)[1]+A(T+3)[2]; vmcnt(2) leaves only
// A(T+3) in flight => B(T+1) and A(T+2) complete before the end barrier.

#define A_LOAD(T, R0, R1)                                                   \
  {                                                                         \
    int kst = (T) * 32;                                                     \
    int row0 = tid >> 2, cc0 = tid & 3;                                     \
    int gc0 = (cc0 ^ ((row0 >> 1) & 3)) * 8;                                \
    const float* ap0 = &Ag[(size_t)(m0 + row0) * 1024 + kst + gc0];         \
    R0 = *reinterpret_cast<const f32x4*>(ap0);                              \
    R1 = *reinterpret_cast<const f32x4*>(ap0 + 4);                          \
  }

#define A_WRITE(T, R0, R1)                                                  \
  {                                                                         \
    short* Ad = &As[(T) & 1][0];                                            \
    *reinterpret_cast<bf16x8*>(&Ad[tid * 8]) = cvt8(R0, R1);                \
  }

#define B_STAGE(T)                                                          \
  {                                                                         \
    int kst = (T) * 32;                                                     \
    short* Bd = &Bs[(T) & 1][0];                                            \
    int row = tid >> 2, cc = tid & 3;                                       \
    int gc = (cc ^ ((row >> 1) & 3)) * 8;                                   \
    gl2lds16(&Bg[(size_t)(n0 + row) * 1024 + kst + gc], &Bd[tid * 8]);      \
  }

// fragment fetch: tile rows are K-contig [256][32] bf16, 2-bit XOR swizzle.
#define FRAG(BUF, ROW, KC)                                                  \
  (*reinterpret_cast<const bf16x8*>(                                        \
      &(BUF)[(ROW) * 32 + (((KC) ^ (((ROW) >> 1) & 3)) * 8)]))

#define BODY(T, DO_B, DO_A, VM, DO_WRITE, W0, W1, L0, L1)                   \
  {                                                                         \
    const short* Ab = &As[(T) & 1][0];                                      \
    const short* Bb = &Bs[(T) & 1][0];                                      \
    bf16x8 a[2][2], b[2][2];                                                \
    _Pragma("unroll") for (int mi = 0; mi < 2; ++mi)                        \
      _Pragma("unroll") for (int kk = 0; kk < 2; ++kk)                      \
        a[mi][kk] = FRAG(Ab, wr + mi * 32 + l31, kk * 2 + l5);              \
    _Pragma("unroll") for (int ni = 0; ni < 2; ++ni)                        \
      _Pragma("unroll") for (int kk = 0; kk < 2; ++kk)                      \
        b[ni][kk] = FRAG(Bb, wc + ni * 32 + l31, kk * 2 + l5);              \
    if (DO_B) B_STAGE((T) + 1);                                             \
    if (DO_A) A_LOAD((T) + 3, L0, L1);                                      \
    asm volatile("s_waitcnt vmcnt(" #VM ")" ::: "memory");                  \
    if (DO_WRITE) A_WRITE((T) + 1, W0, W1);                                 \
    __builtin_amdgcn_s_setprio(1);                                          \
    _Pragma("unroll") for (int kk = 0; kk < 2; ++kk)                        \
      _Pragma("unroll") for (int ni = 0; ni < 2; ++ni)                      \
        _Pragma("unroll") for (int mi = 0; mi < 2; ++mi)                    \
          acc32[mi][ni] = __builtin_amdgcn_mfma_f32_32x32x16_bf16(          \
              a[mi][kk], b[ni][kk], acc32[mi][ni], 0, 0, 0);                \
    __builtin_amdgcn_s_setprio(0);                                          \
    asm volatile("s_waitcnt lgkmcnt(0)" ::: "memory");                      \
    __builtin_amdgcn_s_barrier();                                           \
  }

// set(tile m) = m%3: p=0, q=1, r=2. body T writes set (T+1)%3, loads set T%3.
#define GEMM_CORE()                                                         \
  f32x4 p0, p1, q0, q1, r0, r1;                                             \
  B_STAGE(0); A_LOAD(0, p0, p1);                                            \
  A_LOAD(1, q0, q1);                                                        \
  A_LOAD(2, r0, r1);                                                        \
  asm volatile("s_waitcnt vmcnt(4)" ::: "memory");                          \
  A_WRITE(0, p0, p1);                                                       \
  asm volatile("s_waitcnt lgkmcnt(0)" ::: "memory");                        \
  __builtin_amdgcn_s_barrier();                                             \
  for (int t = 0; t < 27; t += 3) {                                         \
    BODY(t, true, true, 2, true, q0, q1, p0, p1);                           \
    BODY(t + 1, true, true, 2, true, r0, r1, q0, q1);                       \
    BODY(t + 2, true, true, 2, true, p0, p1, r0, r1);                       \
  }                                                                         \
  BODY(27, true, true, 2, true, q0, q1, p0, p1);                            \
  BODY(28, true, true, 2, true, r0, r1, q0, q1);                            \
  BODY(29, true, false, 0, true, p0, p1, p0, p1);                           \
  BODY(30, true, false, 0, true, q0, q1, p0, p1);                           \
  BODY(31, false, false, 0, false, p0, p1, p0, p1);

// ---------------- fused 4-way projection GEMM (f32 activations in) ---------
__global__ __launch_bounds__(1024) void proj_gemm_kernel(
    const float* A0, const float* A1, const float* A2, const float* A3,
    const short* W0, const short* W1, const short* W2, const short* W3,
    const float* c0, const float* c1, const float* c2, const float* c3,
    short* O0, short* O1, short* O2, short* O3) {
  const float* Ap[4] = {A0, A1, A2, A3};
  const short* Wp[4] = {W0, W1, W2, W3};
  const float* bp[4] = {c0, c1, c2, c3};
  short* Op[4] = {O0, O1, O2, O3};

  int id = blockIdx.x;
  int work = (id & 7) * 64 + (id >> 3);
  int z = work >> 7;
  int rem = work & 127;
  int my = rem >> 2;
  int nx = rem & 3;
  const float* Ag = Ap[z];
  const short* Bg = Wp[z];
  const float* bias = bp[z];
  short* Out = Op[z];
  int m0 = my * 256, n0 = nx * 256;

  __shared__ short As[2][8192];
  __shared__ short Bs[2][8192];
  int tid = threadIdx.x;
  int wave = tid >> 6, lane = tid & 63;
  int l31 = lane & 31, l5 = lane >> 5;
  int wr = (wave >> 2) * 64, wc = (wave & 3) * 64;

  f32x16 acc32[2][2] = {};

  GEMM_CORE();

  // epilogue: D col=lane&31 (n), row=(reg&3)+8*(reg>>2)+4*(lane>>5) (m)
#pragma unroll
  for (int ni = 0; ni < 2; ++ni) {
    int n = n0 + wc + ni * 32 + l31;
    float bi = bias[n];
    int hh = n >> 6, d = n & 63;
#pragma unroll
    for (int mi = 0; mi < 2; ++mi)
#pragma unroll
      for (int reg = 0; reg < 16; ++reg) {
        int m = m0 + wr + mi * 32 + (reg & 3) + 8 * (reg >> 2) + 4 * l5;
        int bb = m >> 11, t = m & 2047;
        Out[(size_t)(((bb << 4) + hh) * 2048 + t) * 64 + d] = f2b(acc32[mi][ni][reg] + bi);
      }
  }
}

// ---------------- final GEMM: out(f32) = X(bf16) @ Wo + bo (m97 128²) ------
__global__ __launch_bounds__(256) void final_gemm_kernel(const short* A, const short* Wt,
                                                         const float* bias, float* Out) {
  int id = blockIdx.x;  // 512 blocks
  int work = (id & 7) * 64 + (id >> 3);
  int my = work >> 3, nx = work & 7;
  int m0 = my * 128, n0 = nx * 128;

  __shared__ short Asl[128 * 64];
  __shared__ short Bsl[128 * 64];
  int tid = threadIdx.x;
  int wave = tid >> 6, lane = tid & 63, lg = lane >> 4, lr = lane & 15;
  int wr = (wave >> 1) * 64, wc = (wave & 1) * 64;
  f32x4 acc[4][4] = {};
  int srow = lane >> 3, scol = (lane & 7) * 8;

  for (int k0 = 0; k0 < 1024; k0 += 64) {
    __syncthreads();
#pragma unroll
    for (int i = 0; i < 4; ++i) {
      int c = i * 4 + wave;
      gl2lds16(&A[(size_t)(m0 + c * 8 + srow) * 1024 + k0 + scol], &Asl[c * 512 + lane * 8]);
      gl2lds16(&Wt[(size_t)(n0 + c * 8 + srow) * 1024 + k0 + scol], &Bsl[c * 512 + lane * 8]);
    }
    __syncthreads();
#pragma unroll
    for (int kk = 0; kk < 2; ++kk) {
      bf16x8 a[4], b[4];
      for (int i = 0; i < 4; ++i)
        a[i] = *reinterpret_cast<const bf16x8*>(&Asl[(wr + i * 16 + lr) * 64 + kk * 32 + lg * 8]);
      for (int j = 0; j < 4; ++j)
        b[j] = *reinterpret_cast<const bf16x8*>(&Bsl[(wc + j * 16 + lr) * 64 + kk * 32 + lg * 8]);
      for (int i = 0; i < 4; ++i)
        for (int j = 0; j < 4; ++j)
          acc[i][j] = __builtin_amdgcn_mfma_f32_16x16x32_bf16(a[i], b[j], acc[i][j], 0, 0, 0);
    }
  }
  for (int j = 0; j < 4; ++j) {
    int n = n0 + wc + j * 16 + lr;
    float bi = bias[n];
    for (int i = 0; i < 4; ++i)
      for (int rr = 0; rr < 4; ++rr) {
        int m = m0 + wr + i * 16 + lg * 4 + rr;
        Out[(size_t)m * 1024 + n] = acc[i][j][rr] + bi;
      }
  }
}

// ---------------- KV partials: KVp[bh][c][dk][dv] = sum_t K[t][dk]V[t][dv] -
__global__ __launch_bounds__(256) void kv_kernel(const short* Kp, const short* Vp, float* KVp) {
  int c = blockIdx.x, bh = blockIdx.y;
  int tid = threadIdx.x;
  __shared__ float Ks[32 * 64];
  __shared__ float Vs[32 * 64];
  int srow = tid >> 3, scol = (tid & 7) * 8;
  int dk = tid >> 2, dv0 = (tid & 3) * 16;
  float acc[16] = {};
  for (int sub = 0; sub < 8; ++sub) {
    int tkb = c * 256 + sub * 32;
    __syncthreads();
    bf16x8 kv = *reinterpret_cast<const bf16x8*>(&Kp[(size_t)(bh * 2048 + tkb + srow) * 64 + scol]);
    bf16x8 vv = *reinterpret_cast<const bf16x8*>(&Vp[(size_t)(bh * 2048 + tkb + srow) * 64 + scol]);
    f32x4 ka, kb, va, vb;
#pragma unroll
    for (int j = 0; j < 4; ++j) {
      ka[j] = b2f(kv[j]); kb[j] = b2f(kv[j + 4]);
      va[j] = b2f(vv[j]); vb[j] = b2f(vv[j + 4]);
    }
    *reinterpret_cast<f32x4*>(&Ks[srow * 64 + scol]) = ka;
    *reinterpret_cast<f32x4*>(&Ks[srow * 64 + scol + 4]) = kb;
    *reinterpret_cast<f32x4*>(&Vs[srow * 64 + scol]) = va;
    *reinterpret_cast<f32x4*>(&Vs[srow * 64 + scol + 4]) = vb;
    __syncthreads();
    for (int tok = 0; tok < 32; ++tok) {
      float kval = Ks[tok * 64 + dk];
      f32x4 v0 = *reinterpret_cast<const f32x4*>(&Vs[tok * 64 + dv0]);
      f32x4 v1 = *reinterpret_cast<const f32x4*>(&Vs[tok * 64 + dv0 + 4]);
      f32x4 v2 = *reinterpret_cast<const f32x4*>(&Vs[tok * 64 + dv0 + 8]);
      f32x4 v3 = *reinterpret_cast<const f32x4*>(&Vs[tok * 64 + dv0 + 12]);
#pragma unroll
      for (int j = 0; j < 4; ++j) {
        acc[j] += kval * v0[j];
        acc[4 + j] += kval * v1[j];
        acc[8 + j] += kval * v2[j];
        acc[12 + j] += kval * v3[j];
      }
    }
  }
  float* o = &KVp[(size_t)(bh * 8 + c) * 4096 + dk * 64 + dv0];
  for (int j = 0; j < 16; ++j) o[j] = acc[j];
}

// ---------------- reduce partials, store TRANSPOSED bf16: KVt[dv][dk] ------
__global__ __launch_bounds__(256) void kvred_kernel(const float* KVp, short* KVt) {
  int bh = blockIdx.x;
  for (int e = threadIdx.x; e < 4096; e += 256) {
    float s = 0.f;
    for (int cc = 0; cc < 8; ++cc) s += KVp[(size_t)(bh * 8 + cc) * 4096 + e];
    int dk = e >> 6, dv = e & 63;
    KVt[(size_t)bh * 4096 + dv * 64 + dk] = f2b(s);
  }
}

// ---------------- fused beta + combine -------------------------------------
// KVBLK=128, double-buffered, key-partitioned waves (round-9 structure).
__global__ __launch_bounds__(256) void beta_combine_kernel(
    const short* Qp, const short* Kp, const short* Sp, const short* KVt, short* X) {
  int bh = blockIdx.y, q0 = blockIdx.x * 64;
  int b = bh >> 4, h = bh & 15;
  int tid = threadIdx.x;
  __shared__ float lsm[64];
  __shared__ float red[4][64];
  __shared__ float betaL[64];
  __shared__ short Ks[2][128 * 64];

  const short* Kb = Kp + (size_t)bh * 2048 * 64;
  int srow = tid >> 3, schunk = tid & 7;
  int sxor = (schunk ^ (srow & 7)) * 8;

  // stage tile 0 early: its latency hides under the lang phase.
#pragma unroll
  for (int cc = 0; cc < 4; ++cc)
    gl2lds16(&Kb[(size_t)(cc * 32 + srow) * 64 + sxor], &Ks[0][cc * 2048 + tid * 8]);

  {  // lang: lsm = SCALE*LOG2E * dot(Q_row, S_row)  (exp2-ready)
    int row = tid >> 2, seg = tid & 3;
    const short* qr = Qp + (size_t)(bh * 2048 + q0 + row) * 64 + seg * 16;
    const short* sr = Sp + (size_t)(bh * 2048 + q0 + row) * 64 + seg * 16;
    float sum = 0.f;
    for (int cc = 0; cc < 2; ++cc) {
      bf16x8 qv = reinterpret_cast<const bf16x8*>(qr)[cc];
      bf16x8 sv = reinterpret_cast<const bf16x8*>(sr)[cc];
      for (int j = 0; j < 8; ++j) sum += b2f(qv[j]) * b2f(sv[j]);
    }
    sum += __shfl_xor(sum, 1);
    sum += __shfl_xor(sum, 2);
    if (seg == 0) lsm[row] = sum * SCLOG;
  }
  __syncthreads();

  int wave = tid >> 6, lane = tid & 63, lg = lane >> 4, lr = lane & 15;
  const bf16x8* qbase = reinterpret_cast<const bf16x8*>(
      Qp + (size_t)(bh * 2048 + q0 + wave * 16 + lr) * 64);
  bf16x8 a0 = qbase[lg];
  bf16x8 a1 = qbase[4 + lg];
  bf16x8 as0[4], as1[4];
#pragma unroll
  for (int qt = 0; qt < 4; ++qt) {
    const bf16x8* qb = reinterpret_cast<const bf16x8*>(
        Qp + (size_t)(bh * 2048 + q0 + qt * 16 + lr) * 64);
    bf16x8 t0 = qb[lg], t1 = qb[4 + lg];
#pragma unroll
    for (int j = 0; j < 8; ++j) {
      as0[qt][j] = f2b(b2f(t0[j]) * SCLOG);
      as1[qt][j] = f2b(b2f(t1[j]) * SCLOG);
    }
  }

  float s[4][4] = {};
  for (int t = 0; t < 16; ++t) {
    __builtin_amdgcn_s_barrier();
    if (t < 15) {
      const short* src = Kb + (size_t)(t + 1) * 8192;
      short* dst = &Ks[(t + 1) & 1][0];
#pragma unroll
      for (int cc = 0; cc < 4; ++cc)
        gl2lds16(&src[(size_t)(cc * 32 + srow) * 64 + sxor], &dst[cc * 2048 + tid * 8]);
      asm volatile("s_waitcnt vmcnt(4)" ::: "memory");
    } else {
      asm volatile("s_waitcnt vmcnt(0)" ::: "memory");
    }
    __builtin_amdgcn_s_barrier();
    __builtin_amdgcn_sched_barrier(0);
    const short* Kbuf = &Ks[t & 1][0];
    f32x4 sc[4][2];
    __builtin_amdgcn_s_setprio(1);
#pragma unroll
    for (int kt = 0; kt < 2; ++kt) {
      int row = wave * 32 + kt * 16 + lr;
      int xs = row & 7;
      bf16x8 b0 = *reinterpret_cast<const bf16x8*>(&Kbuf[row * 64 + ((lg ^ xs) * 8)]);
      bf16x8 b1 = *reinterpret_cast<const bf16x8*>(&Kbuf[row * 64 + (((4 + lg) ^ xs) * 8)]);
#pragma unroll
      for (int qt = 0; qt < 4; ++qt) {
        f32x4 z = {0.f, 0.f, 0.f, 0.f};
        z = __builtin_amdgcn_mfma_f32_16x16x32_bf16(as0[qt], b0, z, 0, 0, 0);
        z = __builtin_amdgcn_mfma_f32_16x16x32_bf16(as1[qt], b1, z, 0, 0, 0);
        sc[qt][kt] = z;
      }
    }
    __builtin_amdgcn_s_setprio(0);
#pragma unroll
    for (int qt = 0; qt < 4; ++qt)
#pragma unroll
      for (int kt = 0; kt < 2; ++kt) {
        s[qt][0] += fexp2(sc[qt][kt][0]);
        s[qt][1] += fexp2(sc[qt][kt][1]);
        s[qt][2] += fexp2(sc[qt][kt][2]);
        s[qt][3] += fexp2(sc[qt][kt][3]);
      }
  }
#pragma unroll
  for (int qt = 0; qt < 4; ++qt)
#pragma unroll
    for (int rr = 0; rr < 4; ++rr)
      for (int m = 1; m < 16; m <<= 1) s[qt][rr] += __shfl_xor(s[qt][rr], m);
  if (lr == 0) {
#pragma unroll
    for (int qt = 0; qt < 4; ++qt)
#pragma unroll
      for (int rr = 0; rr < 4; ++rr)
        red[wave][qt * 16 + lg * 4 + rr] = s[qt][rr];
  }
  __syncthreads();
  if (tid < 64) {
    float tot = red[0][tid] + red[1][tid] + red[2][tid] + red[3][tid];
    float el = fexp2(lsm[tid]);
    betaL[tid] = el / (tot + el);
  }
  __syncthreads();
  float bt[4];
#pragma unroll
  for (int rr = 0; rr < 4; ++rr) bt[rr] = betaL[wave * 16 + lg * 4 + rr];

  const short* kvb = KVt + (size_t)bh * 4096;
#pragma unroll
  for (int nt = 0; nt < 4; ++nt) {
    const bf16x8* bb8 = reinterpret_cast<const bf16x8*>(&kvb[(nt * 16 + lr) * 64]);
    bf16x8 b0 = bb8[lg], b1 = bb8[4 + lg];
    f32x4 z = {0.f, 0.f, 0.f, 0.f};
    z = __builtin_amdgcn_mfma_f32_16x16x32_bf16(a0, b0, z, 0, 0, 0);
    z = __builtin_amdgcn_mfma_f32_16x16x32_bf16(a1, b1, z, 0, 0, 0);
#pragma unroll
    for (int rr = 0; rr < 4; ++rr) {
      int rl = wave * 16 + lg * 4 + rr;
      int q = q0 + rl;
      float sv = b2f(Sp[(size_t)(bh * 2048 + q) * 64 + nt * 16 + lr]);
      float val = bt[rr] * sv + (1.0f - bt[rr]) * (SCALE * z[rr]);
      X[(size_t)(b * 2048 + q) * 1024 + h * 64 + nt * 16 + lr] = f2b(val);
    }
  }
}

extern "C" void kernel_launch(void* const* d_in, const int* in_sizes, int n_in,
                              void* d_out, int out_size, void* d_ws, size_t ws_size,
                              hipStream_t stream) {
  const float* queries = (const float*)d_in[0];
  const float* keys = (const float*)d_in[1];
  const float* values = (const float*)d_in[2];
  const float* langf = (const float*)d_in[3];
  const float* Wq = (const float*)d_in[4];
  const float* bq = (const float*)d_in[5];
  const float* Wk = (const float*)d_in[6];
  const float* bk = (const float*)d_in[7];
  const float* Wv = (const float*)d_in[8];
  const float* bv = (const float*)d_in[9];
  const float* Ws = (const float*)d_in[10];
  const float* bs = (const float*)d_in[11];
  const float* Wo = (const float*)d_in[12];
  const float* bo = (const float*)d_in[13];
  float* out = (float*)d_out;

  char* ws = (char*)d_ws;
  const size_t MB = 1ull << 20;
  short* Wqt = (short*)(ws + 0 * MB);
  short* Wkt = (short*)(ws + 2 * MB);
  short* Wvt = (short*)(ws + 4 * MB);
  short* Wst = (short*)(ws + 6 * MB);
  short* Wot = (short*)(ws + 8 * MB);
  short* Qp = (short*)(ws + 10 * MB);   // (B,H,2048,64) bf16
  short* Kp = (short*)(ws + 26 * MB);
  short* Vp = (short*)(ws + 42 * MB);
  short* Sp = (short*)(ws + 58 * MB);
  short* X = (short*)(ws + 74 * MB);    // (B*NQ, 1024) bf16
  float* KVp = (float*)(ws + 90 * MB);
  short* KVt = (short*)(ws + 98 * MB);

  wtrans_kernel<<<dim3(16, 16, 5), 256, 0, stream>>>(Wq, Wk, Wv, Ws, Wo, Wqt, Wkt, Wvt, Wst, Wot);
  proj_gemm_kernel<<<512, 1024, 0, stream>>>(queries, keys, values, langf,
                                             Wqt, Wkt, Wvt, Wst, bq, bk, bv, bs,
                                             Qp, Kp, Vp, Sp);
  kv_kernel<<<dim3(8, 64), 256, 0, stream>>>(Kp, Vp, KVp);
  kvred_kernel<<<64, 256, 0, stream>>>(KVp, KVt);
  beta_combine_kernel<<<dim3(32, 64), 256, 0, stream>>>(Qp, Kp, Sp, KVt, X);
  final_gemm_kernel<<<512, 256, 0, stream>>>(X, Wot, bo, out);
}

// Round 18
// 228.448 us; speedup vs baseline: 1.8098x; 1.8098x over previous
//
#include <hip/hip_runtime.h>

// B=4, NQ=NK=2048, D_MODEL=1024, H=16, D_K=D_V=64; M = 8192.
// att_v uses PRE-softmax scores => att_v = scale * Q @ (K^T V).
// beta only needs row exp-sums of scores.
//
// ROUND 17: exact revert to round-13/15 config (best measured 228.8 us).
// Residency model (closed): proj wave footprint = 128 VGPR + 128 AGPR =
// 256 unified regs/wave -> 8 waves/CU cap (m69). 16-wave variant needs
// <=128 total/wave -> compiler squeezed VGPR to 64 -> 406 MB scratch.
// Occupancy axis is register-bound in both directions; proj ~103 us is
// this structure's floor (vmcnt depth x2 null, LDS-residency null,
// bank-swizzle at aligned 4-way floor, MFMA shape done +15%).

#define SCALE 0.125f
#define LOG2E 1.44269504088896f
#define SCLOG 0.18033688011112042f  // SCALE * LOG2E

typedef __attribute__((ext_vector_type(8))) short bf16x8;
typedef __attribute__((ext_vector_type(4))) short s16x4;
typedef __attribute__((ext_vector_type(4))) float f32x4;
typedef __attribute__((ext_vector_type(16))) float f32x16;

__device__ __forceinline__ float b2f(short x) {
  return __uint_as_float(((unsigned)(unsigned short)x) << 16);
}
__device__ __forceinline__ short f2b(float x) {
  unsigned u = __float_as_uint(x);
  unsigned r = (u + 0x7fffu + ((u >> 16) & 1u)) >> 16;
  return (short)r;
}
// native 2^x (v_exp_f32); inputs here are far from denormal/overflow edges.
__device__ __forceinline__ float fexp2(float x) {
  float r;
  asm("v_exp_f32 %0, %1" : "=v"(r) : "v"(x));
  return r;
}
// 8x f32 -> bf16x8 via packed converts (RTNE).
__device__ __forceinline__ bf16x8 cvt8(f32x4 lo, f32x4 hi) {
  unsigned u0, u1, u2, u3;
  asm("v_cvt_pk_bf16_f32 %0, %1, %2" : "=v"(u0) : "v"(lo[0]), "v"(lo[1]));
  asm("v_cvt_pk_bf16_f32 %0, %1, %2" : "=v"(u1) : "v"(lo[2]), "v"(lo[3]));
  asm("v_cvt_pk_bf16_f32 %0, %1, %2" : "=v"(u2) : "v"(hi[0]), "v"(hi[1]));
  asm("v_cvt_pk_bf16_f32 %0, %1, %2" : "=v"(u3) : "v"(hi[2]), "v"(hi[3]));
  union { unsigned u[4]; bf16x8 v; } r;
  r.u[0] = u0; r.u[1] = u1; r.u[2] = u2; r.u[3] = u3;
  return r.v;
}

// async global->LDS, 16B per lane. LDS dest must be uniform_base + lane*16.
__device__ __forceinline__ void gl2lds16(const short* g, short* l) {
  __builtin_amdgcn_global_load_lds(
      (const __attribute__((address_space(1))) unsigned int*)g,
      (__attribute__((address_space(3))) unsigned int*)l, 16, 0, 0);
}

// ---------------- weights: Wt[n][k] = bf16(W[k][n]), 1024x1024 each --------
__global__ __launch_bounds__(256) void wtrans_kernel(
    const float* W0, const float* W1, const float* W2, const float* W3, const float* W4,
    short* O0, short* O1, short* O2, short* O3, short* O4) {
  const float* Wp[5] = {W0, W1, W2, W3, W4};
  short* Op[5] = {O0, O1, O2, O3, O4};
  const float* W = Wp[blockIdx.z];
  short* O = Op[blockIdx.z];
  int n0 = blockIdx.x * 64, k0 = blockIdx.y * 64;
  __shared__ float ts[64 * 68];
  int tid = threadIdx.x;
  int r = tid >> 4, c = (tid & 15) * 4;
  for (int ir = 0; ir < 4; ++ir) {
    f32x4 v = *reinterpret_cast<const f32x4*>(&W[(size_t)(k0 + r + ir * 16) * 1024 + n0 + c]);
    *reinterpret_cast<f32x4*>(&ts[(r + ir * 16) * 68 + c]) = v;
  }
  __syncthreads();
  for (int ir = 0; ir < 4; ++ir) {
    int n = r + ir * 16;
    s16x4 o;
    for (int j = 0; j < 4; ++j) o[j] = f2b(ts[(c + j) * 68 + n]);
    *reinterpret_cast<s16x4*>(&O[(size_t)(n0 + n) * 1024 + k0 + c]) = o;
  }
}

// ============ 256x256 GEMM core, f32 A reg-staged + bf16 B gl2lds ==========
// 512 thr = 8 waves (2Mx4N). BK=32. A: depth-3 via 3 register sets (p,q,r),
// 2 LDS buffers. B: 2 LDS buffers, staged at T+1. 64 KB LDS total.
// Inner compute: v_mfma_f32_32x32x16_bf16 (16 MFMA/body; +15% ceiling).
// A/B fragment: lane holds row=lane&31, k=(lane>>5)*8 (+kk*16), 8 contiguous.
// C/D: col=lane&31, row=(reg&3)+8*(reg>>2)+4*(lane>>5)  [guide m74/m101].

#define A_LOAD(T, R0, R1, R2, R3)                                           \
  {                                                                         \
    int kst = (T) * 32;                                                     \
    int row0 = tid >> 2, cc0 = tid & 3;                                     \
    int gc0 = (cc0 ^ ((row0 >> 1) & 3)) * 8;                                \
    const float* ap0 = &Ag[(size_t)(m0 + row0) * 1024 + kst + gc0];         \
    R0 = *reinterpret_cast<const f32x4*>(ap0);                              \
    R1 = *reinterpret_cast<const f32x4*>(ap0 + 4);                          \
    int row1 = row0 + 128;                                                  \
    int gc1 = (cc0 ^ ((row1 >> 1) & 3)) * 8;                                \
    const float* ap1 = &Ag[(size_t)(m0 + row1) * 1024 + kst + gc1];         \
    R2 = *reinterpret_cast<const f32x4*>(ap1);                              \
    R3 = *reinterpret_cast<const f32x4*>(ap1 + 4);                          \
  }

#define A_WRITE(T, R0, R1, R2, R3)                                          \
  {                                                                         \
    short* Ad = &As[(T) & 1][0];                                            \
    *reinterpret_cast<bf16x8*>(&Ad[tid * 8]) = cvt8(R0, R1);                \
    *reinterpret_cast<bf16x8*>(&Ad[(tid + 512) * 8]) = cvt8(R2, R3);        \
  }

#define B_STAGE(T)                                                          \
  {                                                                         \
    int kst = (T) * 32;                                                     \
    short* Bd = &Bs[(T) & 1][0];                                            \
    _Pragma("unroll") for (int it = 0; it < 2; ++it) {                      \
      int s = tid + it * 512;                                               \
      int row = s >> 2, cc = s & 3;                                         \
      int gc = (cc ^ ((row >> 1) & 3)) * 8;                                 \
      gl2lds16(&Bg[(size_t)(n0 + row) * 1024 + kst + gc], &Bd[s * 8]);      \
    }                                                                       \
  }

// fragment fetch helper: tile rows are K-contig [256][32] bf16, swizzled.
#define FRAG(BUF, ROW, KC)                                                  \
  (*reinterpret_cast<const bf16x8*>(                                        \
      &(BUF)[(ROW) * 32 + (((KC) ^ (((ROW) >> 1) & 3)) * 8)]))

#define BODY(T, DO_B, DO_A, VM, DO_WRITE, W0, W1, W2, W3, L0, L1, L2, L3)   \
  {                                                                         \
    const short* Ab = &As[(T) & 1][0];                                      \
    const short* Bb = &Bs[(T) & 1][0];                                      \
    bf16x8 a[2][2], b[2][2];                                                \
    _Pragma("unroll") for (int mi = 0; mi < 2; ++mi)                        \
      _Pragma("unroll") for (int kk = 0; kk < 2; ++kk)                      \
        a[mi][kk] = FRAG(Ab, wr + mi * 32 + l31, kk * 2 + l5);              \
    _Pragma("unroll") for (int ni = 0; ni < 2; ++ni)                        \
      _Pragma("unroll") for (int kk = 0; kk < 2; ++kk)                      \
        b[ni][kk] = FRAG(Bb, wc + ni * 32 + l31, kk * 2 + l5);              \
    if (DO_B) B_STAGE((T) + 1);                                             \
    __builtin_amdgcn_s_setprio(1);                                          \
    _Pragma("unroll") for (int kk = 0; kk < 2; ++kk)                        \
      _Pragma("unroll") for (int ni = 0; ni < 2; ++ni)                      \
        _Pragma("unroll") for (int mi = 0; mi < 2; ++mi)                    \
          acc32[mi][ni] = __builtin_amdgcn_mfma_f32_32x32x16_bf16(          \
              a[mi][kk], b[ni][kk], acc32[mi][ni], 0, 0, 0);                \
    __builtin_amdgcn_s_setprio(0);                                          \
    __builtin_amdgcn_s_barrier();                                           \
    bf16x8 a2[2][2];                                                        \
    _Pragma("unroll") for (int mi = 0; mi < 2; ++mi)                        \
      _Pragma("unroll") for (int kk = 0; kk < 2; ++kk)                      \
        a2[mi][kk] = FRAG(Ab, wr + 64 + mi * 32 + l31, kk * 2 + l5);        \
    if (DO_A) A_LOAD((T) + 3, L0, L1, L2, L3);                              \
    asm volatile("s_waitcnt vmcnt(" #VM ")" ::: "memory");                  \
    if (DO_WRITE) A_WRITE((T) + 1, W0, W1, W2, W3);                         \
    __builtin_amdgcn_s_setprio(1);                                          \
    _Pragma("unroll") for (int kk = 0; kk < 2; ++kk)                        \
      _Pragma("unroll") for (int ni = 0; ni < 2; ++ni)                      \
        _Pragma("unroll") for (int mi = 0; mi < 2; ++mi)                    \
          acc32[mi + 2][ni] = __builtin_amdgcn_mfma_f32_32x32x16_bf16(      \
              a2[mi][kk], b[ni][kk], acc32[mi + 2][ni], 0, 0, 0);           \
    __builtin_amdgcn_s_setprio(0);                                          \
    asm volatile("s_waitcnt lgkmcnt(0)" ::: "memory");                      \
    __builtin_amdgcn_s_barrier();                                           \
  }

// set(tile m) = m%3: p=0, q=1, r=2. body T writes set (T+1)%3, loads set T%3.
#define GEMM_CORE()                                                         \
  f32x4 p0, p1, p2, p3, q0, q1, q2, q3, r0, r1, r2, r3;                     \
  B_STAGE(0); A_LOAD(0, p0, p1, p2, p3);                                    \
  A_LOAD(1, q0, q1, q2, q3);                                                \
  A_LOAD(2, r0, r1, r2, r3);                                                \
  asm volatile("s_waitcnt vmcnt(8)" ::: "memory");                          \
  A_WRITE(0, p0, p1, p2, p3);                                               \
  asm volatile("s_waitcnt lgkmcnt(0)" ::: "memory");                        \
  __builtin_amdgcn_s_barrier();                                             \
  for (int t = 0; t < 27; t += 3) {                                         \
    BODY(t, true, true, 4, true, q0, q1, q2, q3, p0, p1, p2, p3);           \
    BODY(t + 1, true, true, 4, true, r0, r1, r2, r3, q0, q1, q2, q3);       \
    BODY(t + 2, true, true, 4, true, p0, p1, p2, p3, r0, r1, r2, r3);       \
  }                                                                         \
  BODY(27, true, true, 4, true, q0, q1, q2, q3, p0, p1, p2, p3);            \
  BODY(28, true, true, 4, true, r0, r1, r2, r3, q0, q1, q2, q3);            \
  BODY(29, true, false, 0, true, p0, p1, p2, p3, p0, p1, p2, p3);           \
  BODY(30, true, false, 0, true, q0, q1, q2, q3, p0, p1, p2, p3);           \
  BODY(31, false, false, 0, false, p0, p1, p2, p3, p0, p1, p2, p3);

// ---------------- fused 4-way projection GEMM (f32 activations in) ---------
__global__ __launch_bounds__(512, 2) void proj_gemm_kernel(
    const float* A0, const float* A1, const float* A2, const float* A3,
    const short* W0, const short* W1, const short* W2, const short* W3,
    const float* c0, const float* c1, const float* c2, const float* c3,
    short* O0, short* O1, short* O2, short* O3) {
  const float* Ap[4] = {A0, A1, A2, A3};
  const short* Wp[4] = {W0, W1, W2, W3};
  const float* bp[4] = {c0, c1, c2, c3};
  short* Op[4] = {O0, O1, O2, O3};

  int id = blockIdx.x;
  int work = (id & 7) * 64 + (id >> 3);
  int z = work >> 7;
  int rem = work & 127;
  int my = rem >> 2;
  int nx = rem & 3;
  const float* Ag = Ap[z];
  const short* Bg = Wp[z];
  const float* bias = bp[z];
  short* Out = Op[z];
  int m0 = my * 256, n0 = nx * 256;

  __shared__ short As[2][8192];
  __shared__ short Bs[2][8192];
  int tid = threadIdx.x;
  int wave = tid >> 6, lane = tid & 63;
  int l31 = lane & 31, l5 = lane >> 5;
  int wr = (wave >> 2) * 128, wc = (wave & 3) * 64;

  f32x16 acc32[4][2] = {};

  GEMM_CORE();

  // epilogue: D col=lane&31 (n), row=(reg&3)+8*(reg>>2)+4*(lane>>5) (m)
#pragma unroll
  for (int ni = 0; ni < 2; ++ni) {
    int n = n0 + wc + ni * 32 + l31;
    float bi = bias[n];
    int hh = n >> 6, d = n & 63;
#pragma unroll
    for (int mi = 0; mi < 4; ++mi)
#pragma unroll
      for (int reg = 0; reg < 16; ++reg) {
        int m = m0 + wr + mi * 32 + (reg & 3) + 8 * (reg >> 2) + 4 * l5;
        int bb = m >> 11, t = m & 2047;
        Out[(size_t)(((bb << 4) + hh) * 2048 + t) * 64 + d] = f2b(acc32[mi][ni][reg] + bi);
      }
  }
}

// ---------------- final GEMM: out(f32) = X(bf16) @ Wo + bo (m97 128²) ------
__global__ __launch_bounds__(256) void final_gemm_kernel(const short* A, const short* Wt,
                                                         const float* bias, float* Out) {
  int id = blockIdx.x;  // 512 blocks
  int work = (id & 7) * 64 + (id >> 3);
  int my = work >> 3, nx = work & 7;
  int m0 = my * 128, n0 = nx * 128;

  __shared__ short Asl[128 * 64];
  __shared__ short Bsl[128 * 64];
  int tid = threadIdx.x;
  int wave = tid >> 6, lane = tid & 63, lg = lane >> 4, lr = lane & 15;
  int wr = (wave >> 1) * 64, wc = (wave & 1) * 64;
  f32x4 acc[4][4] = {};
  int srow = lane >> 3, scol = (lane & 7) * 8;

  for (int k0 = 0; k0 < 1024; k0 += 64) {
    __syncthreads();
#pragma unroll
    for (int i = 0; i < 4; ++i) {
      int c = i * 4 + wave;
      gl2lds16(&A[(size_t)(m0 + c * 8 + srow) * 1024 + k0 + scol], &Asl[c * 512 + lane * 8]);
      gl2lds16(&Wt[(size_t)(n0 + c * 8 + srow) * 1024 + k0 + scol], &Bsl[c * 512 + lane * 8]);
    }
    __syncthreads();
#pragma unroll
    for (int kk = 0; kk < 2; ++kk) {
      bf16x8 a[4], b[4];
      for (int i = 0; i < 4; ++i)
        a[i] = *reinterpret_cast<const bf16x8*>(&Asl[(wr + i * 16 + lr) * 64 + kk * 32 + lg * 8]);
      for (int j = 0; j < 4; ++j)
        b[j] = *reinterpret_cast<const bf16x8*>(&Bsl[(wc + j * 16 + lr) * 64 + kk * 32 + lg * 8]);
      for (int i = 0; i < 4; ++i)
        for (int j = 0; j < 4; ++j)
          acc[i][j] = __builtin_amdgcn_mfma_f32_16x16x32_bf16(a[i], b[j], acc[i][j], 0, 0, 0);
    }
  }
  for (int j = 0; j < 4; ++j) {
    int n = n0 + wc + j * 16 + lr;
    float bi = bias[n];
    for (int i = 0; i < 4; ++i)
      for (int rr = 0; rr < 4; ++rr) {
        int m = m0 + wr + i * 16 + lg * 4 + rr;
        Out[(size_t)m * 1024 + n] = acc[i][j][rr] + bi;
      }
  }
}

// ---------------- KV partials: KVp[bh][c][dk][dv] = sum_t K[t][dk]V[t][dv] -
__global__ __launch_bounds__(256) void kv_kernel(const short* Kp, const short* Vp, float* KVp) {
  int c = blockIdx.x, bh = blockIdx.y;
  int tid = threadIdx.x;
  __shared__ float Ks[32 * 64];
  __shared__ float Vs[32 * 64];
  int srow = tid >> 3, scol = (tid & 7) * 8;
  int dk = tid >> 2, dv0 = (tid & 3) * 16;
  float acc[16] = {};
  for (int sub = 0; sub < 8; ++sub) {
    int tkb = c * 256 + sub * 32;
    __syncthreads();
    bf16x8 kv = *reinterpret_cast<const bf16x8*>(&Kp[(size_t)(bh * 2048 + tkb + srow) * 64 + scol]);
    bf16x8 vv = *reinterpret_cast<const bf16x8*>(&Vp[(size_t)(bh * 2048 + tkb + srow) * 64 + scol]);
    f32x4 ka, kb, va, vb;
#pragma unroll
    for (int j = 0; j < 4; ++j) {
      ka[j] = b2f(kv[j]); kb[j] = b2f(kv[j + 4]);
      va[j] = b2f(vv[j]); vb[j] = b2f(vv[j + 4]);
    }
    *reinterpret_cast<f32x4*>(&Ks[srow * 64 + scol]) = ka;
    *reinterpret_cast<f32x4*>(&Ks[srow * 64 + scol + 4]) = kb;
    *reinterpret_cast<f32x4*>(&Vs[srow * 64 + scol]) = va;
    *reinterpret_cast<f32x4*>(&Vs[srow * 64 + scol + 4]) = vb;
    __syncthreads();
    for (int tok = 0; tok < 32; ++tok) {
      float kval = Ks[tok * 64 + dk];
      f32x4 v0 = *reinterpret_cast<const f32x4*>(&Vs[tok * 64 + dv0]);
      f32x4 v1 = *reinterpret_cast<const f32x4*>(&Vs[tok * 64 + dv0 + 4]);
      f32x4 v2 = *reinterpret_cast<const f32x4*>(&Vs[tok * 64 + dv0 + 8]);
      f32x4 v3 = *reinterpret_cast<const f32x4*>(&Vs[tok * 64 + dv0 + 12]);
#pragma unroll
      for (int j = 0; j < 4; ++j) {
        acc[j] += kval * v0[j];
        acc[4 + j] += kval * v1[j];
        acc[8 + j] += kval * v2[j];
        acc[12 + j] += kval * v3[j];
      }
    }
  }
  float* o = &KVp[(size_t)(bh * 8 + c) * 4096 + dk * 64 + dv0];
  for (int j = 0; j < 16; ++j) o[j] = acc[j];
}

// ---------------- reduce partials, store TRANSPOSED bf16: KVt[dv][dk] ------
__global__ __launch_bounds__(256) void kvred_kernel(const float* KVp, short* KVt) {
  int bh = blockIdx.x;
  for (int e = threadIdx.x; e < 4096; e += 256) {
    float s = 0.f;
    for (int cc = 0; cc < 8; ++cc) s += KVp[(size_t)(bh * 8 + cc) * 4096 + e];
    int dk = e >> 6, dv = e & 63;
    KVt[(size_t)bh * 4096 + dv * 64 + dk] = f2b(s);
  }
}

// ---------------- fused beta + combine -------------------------------------
// KVBLK=128, double-buffered, key-partitioned waves (round-9 structure).
__global__ __launch_bounds__(256) void beta_combine_kernel(
    const short* Qp, const short* Kp, const short* Sp, const short* KVt, short* X) {
  int bh = blockIdx.y, q0 = blockIdx.x * 64;
  int b = bh >> 4, h = bh & 15;
  int tid = threadIdx.x;
  __shared__ float lsm[64];
  __shared__ float red[4][64];
  __shared__ float betaL[64];
  __shared__ short Ks[2][128 * 64];

  const short* Kb = Kp + (size_t)bh * 2048 * 64;
  int srow = tid >> 3, schunk = tid & 7;
  int sxor = (schunk ^ (srow & 7)) * 8;

  // stage tile 0 early: its latency hides under the lang phase.
#pragma unroll
  for (int cc = 0; cc < 4; ++cc)
    gl2lds16(&Kb[(size_t)(cc * 32 + srow) * 64 + sxor], &Ks[0][cc * 2048 + tid * 8]);

  {  // lang: lsm = SCALE*LOG2E * dot(Q_row, S_row)  (exp2-ready)
    int row = tid >> 2, seg = tid & 3;
    const short* qr = Qp + (size_t)(bh * 2048 + q0 + row) * 64 + seg * 16;
    const short* sr = Sp + (size_t)(bh * 2048 + q0 + row) * 64 + seg * 16;
    float sum = 0.f;
    for (int cc = 0; cc < 2; ++cc) {
      bf16x8 qv = reinterpret_cast<const bf16x8*>(qr)[cc];
      bf16x8 sv = reinterpret_cast<const bf16x8*>(sr)[cc];
      for (int j = 0; j < 8; ++j) sum += b2f(qv[j]) * b2f(sv[j]);
    }
    sum += __shfl_xor(sum, 1);
    sum += __shfl_xor(sum, 2);
    if (seg == 0) lsm[row] = sum * SCLOG;
  }
  __syncthreads();

  int wave = tid >> 6, lane = tid & 63, lg = lane >> 4, lr = lane & 15;
  const bf16x8* qbase = reinterpret_cast<const bf16x8*>(
      Qp + (size_t)(bh * 2048 + q0 + wave * 16 + lr) * 64);
  bf16x8 a0 = qbase[lg];
  bf16x8 a1 = qbase[4 + lg];
  bf16x8 as0[4], as1[4];
#pragma unroll
  for (int qt = 0; qt < 4; ++qt) {
    const bf16x8* qb = reinterpret_cast<const bf16x8*>(
        Qp + (size_t)(bh * 2048 + q0 + qt * 16 + lr) * 64);
    bf16x8 t0 = qb[lg], t1 = qb[4 + lg];
#pragma unroll
    for (int j = 0; j < 8; ++j) {
      as0[qt][j] = f2b(b2f(t0[j]) * SCLOG);
      as1[qt][j] = f2b(b2f(t1[j]) * SCLOG);
    }
  }

  float s[4][4] = {};
  for (int t = 0; t < 16; ++t) {
    __builtin_amdgcn_s_barrier();
    if (t < 15) {
      const short* src = Kb + (size_t)(t + 1) * 8192;
      short* dst = &Ks[(t + 1) & 1][0];
#pragma unroll
      for (int cc = 0; cc < 4; ++cc)
        gl2lds16(&src[(size_t)(cc * 32 + srow) * 64 + sxor], &dst[cc * 2048 + tid * 8]);
      asm volatile("s_waitcnt vmcnt(4)" ::: "memory");
    } else {
      asm volatile("s_waitcnt vmcnt(0)" ::: "memory");
    }
    __builtin_amdgcn_s_barrier();
    __builtin_amdgcn_sched_barrier(0);
    const short* Kbuf = &Ks[t & 1][0];
    f32x4 sc[4][2];
    __builtin_amdgcn_s_setprio(1);
#pragma unroll
    for (int kt = 0; kt < 2; ++kt) {
      int row = wave * 32 + kt * 16 + lr;
      int xs = row & 7;
      bf16x8 b0 = *reinterpret_cast<const bf16x8*>(&Kbuf[row * 64 + ((lg ^ xs) * 8)]);
      bf16x8 b1 = *reinterpret_cast<const bf16x8*>(&Kbuf[row * 64 + (((4 + lg) ^ xs) * 8)]);
#pragma unroll
      for (int qt = 0; qt < 4; ++qt) {
        f32x4 z = {0.f, 0.f, 0.f, 0.f};
        z = __builtin_amdgcn_mfma_f32_16x16x32_bf16(as0[qt], b0, z, 0, 0, 0);
        z = __builtin_amdgcn_mfma_f32_16x16x32_bf16(as1[qt], b1, z, 0, 0, 0);
        sc[qt][kt] = z;
      }
    }
    __builtin_amdgcn_s_setprio(0);
#pragma unroll
    for (int qt = 0; qt < 4; ++qt)
#pragma unroll
      for (int kt = 0; kt < 2; ++kt) {
        s[qt][0] += fexp2(sc[qt][kt][0]);
        s[qt][1] += fexp2(sc[qt][kt][1]);
        s[qt][2] += fexp2(sc[qt][kt][2]);
        s[qt][3] += fexp2(sc[qt][kt][3]);
      }
  }
#pragma unroll
  for (int qt = 0; qt < 4; ++qt)
#pragma unroll
    for (int rr = 0; rr < 4; ++rr)
      for (int m = 1; m < 16; m <<= 1) s[qt][rr] += __shfl_xor(s[qt][rr], m);
  if (lr == 0) {
#pragma unroll
    for (int qt = 0; qt < 4; ++qt)
#pragma unroll
      for (int rr = 0; rr < 4; ++rr)
        red[wave][qt * 16 + lg * 4 + rr] = s[qt][rr];
  }
  __syncthreads();
  if (tid < 64) {
    float tot = red[0][tid] + red[1][tid] + red[2][tid] + red[3][tid];
    float el = fexp2(lsm[tid]);
    betaL[tid] = el / (tot + el);
  }
  __syncthreads();
  float bt[4];
#pragma unroll
  for (int rr = 0; rr < 4; ++rr) bt[rr] = betaL[wave * 16 + lg * 4 + rr];

  const short* kvb = KVt + (size_t)bh * 4096;
#pragma unroll
  for (int nt = 0; nt < 4; ++nt) {
    const bf16x8* bb8 = reinterpret_cast<const bf16x8*>(&kvb[(nt * 16 + lr) * 64]);
    bf16x8 b0 = bb8[lg], b1 = bb8[4 + lg];
    f32x4 z = {0.f, 0.f, 0.f, 0.f};
    z = __builtin_amdgcn_mfma_f32_16x16x32_bf16(a0, b0, z, 0, 0, 0);
    z = __builtin_amdgcn_mfma_f32_16x16x32_bf16(a1, b1, z, 0, 0, 0);
#pragma unroll
    for (int rr = 0; rr < 4; ++rr) {
      int rl = wave * 16 + lg * 4 + rr;
      int q = q0 + rl;
      float sv = b2f(Sp[(size_t)(bh * 2048 + q) * 64 + nt * 16 + lr]);
      float val = bt[rr] * sv + (1.0f - bt[rr]) * (SCALE * z[rr]);
      X[(size_t)(b * 2048 + q) * 1024 + h * 64 + nt * 16 + lr] = f2b(val);
    }
  }
}

extern "C" void kernel_launch(void* const* d_in, const int* in_sizes, int n_in,
                              void* d_out, int out_size, void* d_ws, size_t ws_size,
                              hipStream_t stream) {
  const float* queries = (const float*)d_in[0];
  const float* keys = (const float*)d_in[1];
  const float* values = (const float*)d_in[2];
  const float* langf = (const float*)d_in[3];
  const float* Wq = (const float*)d_in[4];
  const float* bq = (const float*)d_in[5];
  const float* Wk = (const float*)d_in[6];
  const float* bk = (const float*)d_in[7];
  const float* Wv = (const float*)d_in[8];
  const float* bv = (const float*)d_in[9];
  const float* Ws = (const float*)d_in[10];
  const float* bs = (const float*)d_in[11];
  const float* Wo = (const float*)d_in[12];
  const float* bo = (const float*)d_in[13];
  float* out = (float*)d_out;

  char* ws = (char*)d_ws;
  const size_t MB = 1ull << 20;
  short* Wqt = (short*)(ws + 0 * MB);
  short* Wkt = (short*)(ws + 2 * MB);
  short* Wvt = (short*)(ws + 4 * MB);
  short* Wst = (short*)(ws + 6 * MB);
  short* Wot = (short*)(ws + 8 * MB);
  short* Qp = (short*)(ws + 10 * MB);   // (B,H,2048,64) bf16
  short* Kp = (short*)(ws + 26 * MB);
  short* Vp = (short*)(ws + 42 * MB);
  short* Sp = (short*)(ws + 58 * MB);
  short* X = (short*)(ws + 74 * MB);    // (B*NQ, 1024) bf16
  float* KVp = (float*)(ws + 90 * MB);
  short* KVt = (short*)(ws + 98 * MB);

  wtrans_kernel<<<dim3(16, 16, 5), 256, 0, stream>>>(Wq, Wk, Wv, Ws, Wo, Wqt, Wkt, Wvt, Wst, Wot);
  proj_gemm_kernel<<<512, 512, 0, stream>>>(queries, keys, values, langf,
                                            Wqt, Wkt, Wvt, Wst, bq, bk, bv, bs,
                                            Qp, Kp, Vp, Sp);
  kv_kernel<<<dim3(8, 64), 256, 0, stream>>>(Kp, Vp, KVp);
  kvred_kernel<<<64, 256, 0, stream>>>(KVp, KVt);
  beta_combine_kernel<<<dim3(32, 64), 256, 0, stream>>>(Qp, Kp, Sp, KVt, X);
  final_gemm_kernel<<<512, 256, 0, stream>>>(X, Wot, bo, out);
}